// Round 4
// baseline (314.184 us; speedup 1.0000x reference)
//
#include <hip/hip_runtime.h>

#define NPOSTS 2048
#define SEQ 64
#define W2V 300
#define NH 5
#define HD 60
#define S2VD 256
#define HIDD 256
#define NEDGE 2047
#define UDIM (NH * W2V)   // 1500

__device__ __forceinline__ float dot4(float4 a, float4 b) {
    return fmaf(a.x, b.x, fmaf(a.y, b.y, fmaf(a.z, b.z, a.w * b.w)));
}

// ---------------- Stage 0: WsWo = Ws @ Wo (256x300), bias2 = Ws@bo + bs ----------------
__global__ __launch_bounds__(256) void k_wfold(
    const float* __restrict__ Ws, const float* __restrict__ Wo,
    const float* __restrict__ bo, const float* __restrict__ bs,
    float* __restrict__ WsWo, float* __restrict__ bias2)
{
    const int cb = blockIdx.x;      // column block: cols 4cb..4cb+3
    const int t = threadIdx.x;      // out row 0..255
    const float* wsr = Ws + (size_t)t * W2V;
    float4 acc = make_float4(0.f, 0.f, 0.f, 0.f);
    for (int k = 0; k < W2V; ++k) {
        float wv = wsr[k];
        const float4 wo4 = *reinterpret_cast<const float4*>(Wo + (size_t)k * W2V + cb * 4);
        acc.x = fmaf(wv, wo4.x, acc.x);
        acc.y = fmaf(wv, wo4.y, acc.y);
        acc.z = fmaf(wv, wo4.z, acc.z);
        acc.w = fmaf(wv, wo4.w, acc.w);
    }
    *reinterpret_cast<float4*>(WsWo + (size_t)t * W2V + cb * 4) = acc;
    if (cb == 0) {
        float b = bs[t];
        for (int k = 0; k < W2V; ++k) b = fmaf(wsr[k], bo[k], b);
        bias2[t] = b;
    }
}

// ---------------- Stage 1a: fused q = Wq@Emb0+bq ; u_h = Wk_h^T q_h  (4 posts/block) ----------------
__global__ __launch_bounds__(320) void k_qu(
    const int* __restrict__ nodeText, const float* __restrict__ embed_w,
    const float* __restrict__ Wqkv, const float* __restrict__ bqkv,
    float* __restrict__ uout)
{
    const int r0 = blockIdx.x * 4;
    const int tid = threadIdx.x;
    __shared__ float sE[4][W2V];
    __shared__ float sQ[4][W2V];

    if (tid < 300) {
        int r = tid / 75, c4 = (tid % 75) * 4;
        int t = nodeText[(size_t)(r0 + r) * SEQ];
        const float4 v = *reinterpret_cast<const float4*>(embed_w + (size_t)t * W2V + c4);
        sE[r][c4] = v.x; sE[r][c4 + 1] = v.y; sE[r][c4 + 2] = v.z; sE[r][c4 + 3] = v.w;
    }
    __syncthreads();

    if (tid < W2V) {
        const float4* wr4 = reinterpret_cast<const float4*>(Wqkv + (size_t)tid * W2V);
        const float4* e0 = reinterpret_cast<const float4*>(&sE[0][0]);
        const float4* e1 = reinterpret_cast<const float4*>(&sE[1][0]);
        const float4* e2 = reinterpret_cast<const float4*>(&sE[2][0]);
        const float4* e3 = reinterpret_cast<const float4*>(&sE[3][0]);
        float b = bqkv[tid];
        float a0 = b, a1 = b, a2 = b, a3 = b;
        for (int c4 = 0; c4 < 75; ++c4) {
            float4 w4 = wr4[c4];
            float4 v0 = e0[c4], v1 = e1[c4], v2 = e2[c4], v3 = e3[c4];
            a0 = fmaf(w4.x, v0.x, a0); a1 = fmaf(w4.x, v1.x, a1);
            a2 = fmaf(w4.x, v2.x, a2); a3 = fmaf(w4.x, v3.x, a3);
            a0 = fmaf(w4.y, v0.y, a0); a1 = fmaf(w4.y, v1.y, a1);
            a2 = fmaf(w4.y, v2.y, a2); a3 = fmaf(w4.y, v3.y, a3);
            a0 = fmaf(w4.z, v0.z, a0); a1 = fmaf(w4.z, v1.z, a1);
            a2 = fmaf(w4.z, v2.z, a2); a3 = fmaf(w4.z, v3.z, a3);
            a0 = fmaf(w4.w, v0.w, a0); a1 = fmaf(w4.w, v1.w, a1);
            a2 = fmaf(w4.w, v2.w, a2); a3 = fmaf(w4.w, v3.w, a3);
        }
        sQ[0][tid] = a0; sQ[1][tid] = a1; sQ[2][tid] = a2; sQ[3][tid] = a3;
    }
    __syncthreads();

    if (tid < W2V) {
        for (int h = 0; h < NH; ++h) {
            const float* wb = Wqkv + (size_t)(W2V + h * HD) * W2V + tid;  // lane-coalesced
            const float* q0 = &sQ[0][h * HD];
            const float* q1 = &sQ[1][h * HD];
            const float* q2 = &sQ[2][h * HD];
            const float* q3 = &sQ[3][h * HD];
            float a0 = 0.f, a1 = 0.f, a2 = 0.f, a3 = 0.f;
            for (int d = 0; d < HD; ++d) {
                float wv = wb[(size_t)d * W2V];
                a0 = fmaf(wv, q0[d], a0);
                a1 = fmaf(wv, q1[d], a1);
                a2 = fmaf(wv, q2[d], a2);
                a3 = fmaf(wv, q3[d], a3);
            }
            uout[(size_t)(r0 + 0) * UDIM + h * W2V + tid] = a0;
            uout[(size_t)(r0 + 1) * UDIM + h * W2V + tid] = a1;
            uout[(size_t)(r0 + 2) * UDIM + h * W2V + tid] = a2;
            uout[(size_t)(r0 + 3) * UDIM + h * W2V + tid] = a3;
        }
    }
}

// ---------------- Stage 1b: per-post scores + softmax + e (2 posts/block, lane-per-token) ----------------
__global__ __launch_bounds__(256) void k_att(
    const int* __restrict__ nodeText, const float* __restrict__ embed_w,
    float* __restrict__ ue)
{
    __shared__ float su[2][UDIM];          // u staged; reused as e-partial buffer
    __shared__ int   stoks[2][SEQ];
    __shared__ float sp[2][2][NH][SEQ];    // score partials (2 column-halves)
    __shared__ float satt[2][NH][SEQ];

    const int p0 = blockIdx.x * 2;
    const int tid = threadIdx.x;
    const int wave = tid >> 6, lane = tid & 63;
    const int wp = wave >> 1;   // post in block
    const int wh = wave & 1;    // half

    if (tid < 2 * SEQ) stoks[tid >> 6][tid & 63] = nodeText[(size_t)(p0 + (tid >> 6)) * SEQ + (tid & 63)];
    {
        const float4* g = reinterpret_cast<const float4*>(ue + (size_t)p0 * UDIM);
        float4* s = reinterpret_cast<float4*>(&su[0][0]);
        for (int i = tid; i < 2 * UDIM / 4; i += 256) s[i] = g[i];
    }
    __syncthreads();

    // --- scores: lane j = token j; column-split across wave pair; u via LDS broadcast ---
    {
        const int tok = stoks[wp][lane];
        const float4* er = reinterpret_cast<const float4*>(embed_w + (size_t)tok * W2V);
        const float4* u4 = reinterpret_cast<const float4*>(&su[wp][0]);
        float a0 = 0.f, a1 = 0.f, a2 = 0.f, a3 = 0.f, a4 = 0.f;
        const int c40 = wh ? 38 : 0, c41 = wh ? 75 : 38;
        for (int c4 = c40; c4 < c41; ++c4) {
            float4 ev = er[c4];
            a0 += dot4(ev, u4[0 * 75 + c4]);
            a1 += dot4(ev, u4[1 * 75 + c4]);
            a2 += dot4(ev, u4[2 * 75 + c4]);
            a3 += dot4(ev, u4[3 * 75 + c4]);
            a4 += dot4(ev, u4[4 * 75 + c4]);
        }
        sp[wp][wh][0][lane] = a0;
        sp[wp][wh][1][lane] = a1;
        sp[wp][wh][2][lane] = a2;
        sp[wp][wh][3][lane] = a3;
        sp[wp][wh][4][lane] = a4;
    }
    __syncthreads();

    // --- softmax: wave with wh==0 per post; one butterfly per head ---
    if (wh == 0) {
        const float SC = 0.12909944487358056f;  // 60^-0.5
        #pragma unroll
        for (int h = 0; h < NH; ++h) {
            float v = (sp[wp][0][h][lane] + sp[wp][1][h][lane]) * SC;
            float m = v;
            #pragma unroll
            for (int off = 32; off > 0; off >>= 1) m = fmaxf(m, __shfl_xor(m, off));
            float e = expf(v - m);
            float s = e;
            #pragma unroll
            for (int off = 32; off > 0; off >>= 1) s += __shfl_xor(s, off);
            satt[wp][h][lane] = e / s;
        }
    }
    __syncthreads();

    // --- e: token-split across wave pair; lane owns column-float4; reduce via su region ---
    {
        const float4 z = make_float4(0.f, 0.f, 0.f, 0.f);
        float4 accA[NH] = {z, z, z, z, z};
        float4 accT[NH] = {z, z, z, z, z};
        const bool tail = lane < 11;
        const int j0 = wh * 32;
        for (int jj = 0; jj < 32; ++jj) {
            int j = j0 + jj;
            const float4* er = reinterpret_cast<const float4*>(embed_w + (size_t)stoks[wp][j] * W2V);
            float4 ea = er[lane];
            float4 eb = tail ? er[64 + lane] : z;
            #pragma unroll
            for (int h = 0; h < NH; ++h) {
                float av = satt[wp][h][j];
                accA[h].x = fmaf(av, ea.x, accA[h].x);
                accA[h].y = fmaf(av, ea.y, accA[h].y);
                accA[h].z = fmaf(av, ea.z, accA[h].z);
                accA[h].w = fmaf(av, ea.w, accA[h].w);
                accT[h].x = fmaf(av, eb.x, accT[h].x);
                accT[h].y = fmaf(av, eb.y, accT[h].y);
                accT[h].z = fmaf(av, eb.z, accT[h].z);
                accT[h].w = fmaf(av, eb.w, accT[h].w);
            }
        }
        float4* ep = reinterpret_cast<float4*>(&su[wp][0]);
        if (wh == 1) {
            #pragma unroll
            for (int h = 0; h < NH; ++h) ep[h * 75 + lane] = accA[h];
            if (tail) {
                #pragma unroll
                for (int h = 0; h < NH; ++h) ep[h * 75 + 64 + lane] = accT[h];
            }
        }
        __syncthreads();
        if (wh == 0) {
            float4* eo = reinterpret_cast<float4*>(ue + (size_t)(p0 + wp) * UDIM);
            #pragma unroll
            for (int h = 0; h < NH; ++h) {
                float4 o = ep[h * 75 + lane];
                o.x += accA[h].x; o.y += accA[h].y; o.z += accA[h].z; o.w += accA[h].w;
                eo[h * 75 + lane] = o;
            }
            if (tail) {
                #pragma unroll
                for (int h = 0; h < NH; ++h) {
                    float4 o = ep[h * 75 + 64 + lane];
                    o.x += accT[h].x; o.y += accT[h].y; o.z += accT[h].z; o.w += accT[h].w;
                    eo[h * 75 + 64 + lane] = o;
                }
            }
        }
    }
}

// ---------------- Stage 1c: o = Wv@e+bv ; s2v = tanh(WsWo@o + bias2) ----------------
__global__ __launch_bounds__(320) void k_oms(
    const float* __restrict__ e, const float* __restrict__ Wqkv, const float* __restrict__ bqkv,
    const float* __restrict__ WsWo, const float* __restrict__ bias2,
    float* __restrict__ s2v_out)
{
    const int r0 = blockIdx.x * 4;
    const int tid = threadIdx.x;
    __shared__ float se[4][UDIM];   // 24 KB
    __shared__ float so[4][W2V];

    {
        const float4* g = reinterpret_cast<const float4*>(e + (size_t)r0 * UDIM);
        float4* s = reinterpret_cast<float4*>(&se[0][0]);
        for (int i = tid; i < 4 * UDIM / 4; i += 320) s[i] = g[i];
    }
    __syncthreads();

    if (tid < W2V) {
        const int h = tid / HD;
        const float4* wr4 = reinterpret_cast<const float4*>(Wqkv + (size_t)(2 * W2V + tid) * W2V);
        const float4* e0 = reinterpret_cast<const float4*>(&se[0][h * W2V]);
        const float4* e1 = reinterpret_cast<const float4*>(&se[1][h * W2V]);
        const float4* e2 = reinterpret_cast<const float4*>(&se[2][h * W2V]);
        const float4* e3 = reinterpret_cast<const float4*>(&se[3][h * W2V]);
        float b = bqkv[2 * W2V + tid];
        float a0 = b, a1 = b, a2 = b, a3 = b;
        for (int c4 = 0; c4 < 75; ++c4) {
            float4 w4 = wr4[c4];
            float4 v0 = e0[c4], v1 = e1[c4], v2 = e2[c4], v3 = e3[c4];
            a0 = fmaf(w4.x, v0.x, a0); a1 = fmaf(w4.x, v1.x, a1);
            a2 = fmaf(w4.x, v2.x, a2); a3 = fmaf(w4.x, v3.x, a3);
            a0 = fmaf(w4.y, v0.y, a0); a1 = fmaf(w4.y, v1.y, a1);
            a2 = fmaf(w4.y, v2.y, a2); a3 = fmaf(w4.y, v3.y, a3);
            a0 = fmaf(w4.z, v0.z, a0); a1 = fmaf(w4.z, v1.z, a1);
            a2 = fmaf(w4.z, v2.z, a2); a3 = fmaf(w4.z, v3.z, a3);
            a0 = fmaf(w4.w, v0.w, a0); a1 = fmaf(w4.w, v1.w, a1);
            a2 = fmaf(w4.w, v2.w, a2); a3 = fmaf(w4.w, v3.w, a3);
        }
        so[0][tid] = a0; so[1][tid] = a1; so[2][tid] = a2; so[3][tid] = a3;
    }
    __syncthreads();

    if (tid < S2VD) {
        const float4* wr4 = reinterpret_cast<const float4*>(WsWo + (size_t)tid * W2V);
        const float4* o0 = reinterpret_cast<const float4*>(&so[0][0]);
        const float4* o1 = reinterpret_cast<const float4*>(&so[1][0]);
        const float4* o2 = reinterpret_cast<const float4*>(&so[2][0]);
        const float4* o3 = reinterpret_cast<const float4*>(&so[3][0]);
        float b = bias2[tid];
        float a0 = b, a1 = b, a2 = b, a3 = b;
        for (int c4 = 0; c4 < 75; ++c4) {
            float4 w4 = wr4[c4];
            float4 v0 = o0[c4], v1 = o1[c4], v2 = o2[c4], v3 = o3[c4];
            a0 = fmaf(w4.x, v0.x, a0); a1 = fmaf(w4.x, v1.x, a1);
            a2 = fmaf(w4.x, v2.x, a2); a3 = fmaf(w4.x, v3.x, a3);
            a0 = fmaf(w4.y, v0.y, a0); a1 = fmaf(w4.y, v1.y, a1);
            a2 = fmaf(w4.y, v2.y, a2); a3 = fmaf(w4.y, v3.y, a3);
            a0 = fmaf(w4.z, v0.z, a0); a1 = fmaf(w4.z, v1.z, a1);
            a2 = fmaf(w4.z, v2.z, a2); a3 = fmaf(w4.z, v3.z, a3);
            a0 = fmaf(w4.w, v0.w, a0); a1 = fmaf(w4.w, v1.w, a1);
            a2 = fmaf(w4.w, v2.w, a2); a3 = fmaf(w4.w, v3.w, a3);
        }
        s2v_out[(size_t)(r0 + 0) * S2VD + tid] = tanhf(a0);
        s2v_out[(size_t)(r0 + 1) * S2VD + tid] = tanhf(a1);
        s2v_out[(size_t)(r0 + 2) * S2VD + tid] = tanhf(a2);
        s2v_out[(size_t)(r0 + 3) * S2VD + tid] = tanhf(a3);
    }
}

// ---------------- Stage 2: GCN branches (blockIdx.y = branch: 0=TD, 1=BU) ----------------

__global__ __launch_bounds__(256) void k_deg(
    const int* __restrict__ eiTD, const int* __restrict__ eiBU, int* __restrict__ deg)
{
    const int b = blockIdx.y;
    const int* ei = b ? eiBU : eiTD;
    int e = blockIdx.x * 256 + threadIdx.x;
    if (e < NEDGE) atomicAdd(&deg[b * NPOSTS + ei[NEDGE + e]], 1);
}

__global__ __launch_bounds__(256) void k_gemm1(
    const float* __restrict__ x, const float* __restrict__ wtd, const float* __restrict__ wbu,
    const float* __restrict__ btd, const float* __restrict__ bbu, const int* __restrict__ deg,
    float* __restrict__ hout, float* __restrict__ cout_)
{
    const int b = blockIdx.y;
    const float* w = b ? wbu : wtd;
    const float* bias = b ? bbu : btd;
    float* hb = hout + (size_t)b * NPOSTS * HIDD;
    float* cb = cout_ + (size_t)b * NPOSTS * HIDD;
    const int* dg = deg + b * NPOSTS;
    const int r0 = blockIdx.x * 16;
    const int tid = threadIdx.x;
    __shared__ float sx[16][S2VD];
    for (int i = tid; i < 16 * S2VD; i += 256)
        sx[i / S2VD][i % S2VD] = x[(size_t)(r0 + i / S2VD) * S2VD + (i % S2VD)];
    __syncthreads();
    float acc[16];
    #pragma unroll
    for (int r = 0; r < 16; ++r) acc[r] = 0.f;
    const float4* wr4 = reinterpret_cast<const float4*>(w + (size_t)tid * S2VD);
    for (int c4 = 0; c4 < 64; ++c4) {
        float4 w4 = wr4[c4];
        #pragma unroll
        for (int r = 0; r < 16; ++r) {
            const float4 v = *reinterpret_cast<const float4*>(&sx[r][c4 * 4]);
            acc[r] = fmaf(w4.x, v.x, acc[r]);
            acc[r] = fmaf(w4.y, v.y, acc[r]);
            acc[r] = fmaf(w4.z, v.z, acc[r]);
            acc[r] = fmaf(w4.w, v.w, acc[r]);
        }
    }
    float bv = bias[tid];
    #pragma unroll
    for (int r = 0; r < 16; ++r) {
        int n = r0 + r;
        float dinv = 1.f / (float)(dg[n] + 1);
        hb[(size_t)n * HIDD + tid] = acc[r];
        cb[(size_t)n * HIDD + tid] = bv + acc[r] * dinv;
    }
}

__global__ __launch_bounds__(256) void k_gemm2(
    const float* __restrict__ c1, const float* __restrict__ w2td, const float* __restrict__ w2bu,
    const float* __restrict__ btd, const float* __restrict__ bbu, const int* __restrict__ deg,
    const float* __restrict__ rootv, float* __restrict__ hout, float* __restrict__ cout_)
{
    const int b = blockIdx.y;
    const float* w = b ? w2bu : w2td;
    const float* bias = b ? bbu : btd;
    const float* xin = c1 + (size_t)b * NPOSTS * HIDD;
    float* hb = hout + (size_t)b * NPOSTS * HIDD;
    float* cb = cout_ + (size_t)b * NPOSTS * HIDD;
    const int* dg = deg + b * NPOSTS;
    const int r0 = blockIdx.x * 16;
    const int tid = threadIdx.x;
    __shared__ float sx[16][HIDD];
    for (int i = tid; i < 16 * HIDD; i += 256)
        sx[i / HIDD][i % HIDD] = fmaxf(xin[(size_t)(r0 + i / HIDD) * HIDD + (i % HIDD)], 0.f);
    __syncthreads();
    float acc[16];
    const float rv = rootv[b * HIDD + tid];
    #pragma unroll
    for (int r = 0; r < 16; ++r) acc[r] = rv;
    const float4* wr4 = reinterpret_cast<const float4*>(w + (size_t)tid * 512);
    for (int c4 = 0; c4 < 64; ++c4) {
        float4 w4 = wr4[c4];
        #pragma unroll
        for (int r = 0; r < 16; ++r) {
            const float4 v = *reinterpret_cast<const float4*>(&sx[r][c4 * 4]);
            acc[r] = fmaf(w4.x, v.x, acc[r]);
            acc[r] = fmaf(w4.y, v.y, acc[r]);
            acc[r] = fmaf(w4.z, v.z, acc[r]);
            acc[r] = fmaf(w4.w, v.w, acc[r]);
        }
    }
    float bv = bias[tid];
    #pragma unroll
    for (int r = 0; r < 16; ++r) {
        int n = r0 + r;
        float dinv = 1.f / (float)(dg[n] + 1);
        hb[(size_t)n * HIDD + tid] = acc[r];
        cb[(size_t)n * HIDD + tid] = bv + acc[r] * dinv;
    }
}

__global__ __launch_bounds__(256) void k_scat(
    const int* __restrict__ eiTD, const int* __restrict__ eiBU,
    const float* __restrict__ h, const int* __restrict__ deg, float* __restrict__ cacc)
{
    const int b = blockIdx.y, e = blockIdx.x, tid = threadIdx.x;
    const int* ei = b ? eiBU : eiTD;
    const int s = ei[e], d = ei[NEDGE + e];
    const int* dg = deg + b * NPOSTS;
    float norm = rsqrtf((float)(dg[s] + 1)) * rsqrtf((float)(dg[d] + 1));
    const float* hb = h + (size_t)b * NPOSTS * HIDD;
    float* cb = cacc + (size_t)b * NPOSTS * HIDD;
    atomicAdd(&cb[(size_t)d * HIDD + tid], norm * hb[(size_t)s * HIDD + tid]);
}

__global__ __launch_bounds__(256) void k_root(
    const float* __restrict__ s2v, const float* __restrict__ c1,
    const float* __restrict__ w2td, const float* __restrict__ w2bu,
    const int* __restrict__ rootPtr, float* __restrict__ rootv, float* __restrict__ c1root)
{
    const int b = blockIdx.y, tid = threadIdx.x;
    const float* w2 = b ? w2bu : w2td;
    const int root = rootPtr[0];
    __shared__ float sx[S2VD];
    sx[tid] = fmaxf(s2v[(size_t)root * S2VD + tid], 0.f);
    __syncthreads();
    const float* cb = c1 + (size_t)b * NPOSTS * HIDD;
    c1root[b * HIDD + tid] = cb[(size_t)root * HIDD + tid];
    const float* wr = w2 + (size_t)tid * 512 + 256;
    float acc = 0.f;
    #pragma unroll 4
    for (int c = 0; c < S2VD; ++c) acc = fmaf(wr[c], sx[c], acc);
    rootv[b * HIDD + tid] = acc;
}

__global__ __launch_bounds__(256) void k_reduce(
    const float* __restrict__ cacc, float* __restrict__ msum)
{
    const int b = blockIdx.y, tid = threadIdx.x;
    const int base = blockIdx.x * 32;
    const float* cb = cacc + (size_t)b * NPOSTS * HIDD;
    float local = 0.f;
    #pragma unroll 4
    for (int r = 0; r < 32; ++r) local += fmaxf(cb[(size_t)(base + r) * HIDD + tid], 0.f);
    atomicAdd(&msum[b * HIDD + tid], local);
}

__global__ __launch_bounds__(256) void k_final(
    const float* __restrict__ c1root, const float* __restrict__ msum,
    const float* __restrict__ fc_w, const float* __restrict__ fc_b, float* __restrict__ outp)
{
    const int tid = threadIdx.x;
    __shared__ float sf[1024];
    for (int k = tid; k < 1024; k += 256) {
        int seg = k >> 8, idx = k & 255;
        float v;
        if (seg == 0)      v = c1root[idx];
        else if (seg == 1) v = msum[idx] * (1.f / (float)NPOSTS);
        else if (seg == 2) v = c1root[256 + idx];
        else               v = msum[256 + idx] * (1.f / (float)NPOSTS);
        sf[k] = v;
    }
    __syncthreads();
    const int t = tid >> 6, lane = tid & 63;
    float part = 0.f;
    for (int k = lane; k < 1024; k += 64) part = fmaf(fc_w[t * 1024 + k], sf[k], part);
    #pragma unroll
    for (int off = 32; off > 0; off >>= 1) part += __shfl_down(part, off);
    if (lane == 0) outp[t] = part + fc_b[t];
}

extern "C" void kernel_launch(void* const* d_in, const int* in_sizes, int n_in,
                              void* d_out, int out_size, void* d_ws, size_t ws_size,
                              hipStream_t stream) {
    (void)in_sizes; (void)n_in; (void)out_size; (void)ws_size;

    const int*   nodeText   = (const int*)d_in[0];
    const int*   eiTD       = (const int*)d_in[1];
    const int*   eiBU       = (const int*)d_in[2];
    const int*   threadIdxP = (const int*)d_in[3];
    const float* embed_w    = (const float*)d_in[5];
    const float* in_proj_w  = (const float*)d_in[6];
    const float* in_proj_b  = (const float*)d_in[7];
    const float* out_proj_w = (const float*)d_in[8];
    const float* out_proj_b = (const float*)d_in[9];
    const float* s2v_w      = (const float*)d_in[10];
    const float* s2v_b      = (const float*)d_in[11];
    const float* td_w1      = (const float*)d_in[12];
    const float* td_b1      = (const float*)d_in[13];
    const float* td_w2      = (const float*)d_in[14];
    const float* td_b2      = (const float*)d_in[15];
    const float* bu_w1      = (const float*)d_in[16];
    const float* bu_b1      = (const float*)d_in[17];
    const float* bu_w2      = (const float*)d_in[18];
    const float* bu_b2      = (const float*)d_in[19];
    const float* fc_w       = (const float*)d_in[20];
    const float* fc_b       = (const float*)d_in[21];
    float* outp = (float*)d_out;

    // workspace layout
    char* w = (char*)d_ws;
    int*   deg    = (int*)w;                          // 16384 B
    float* msum   = (float*)(w + 16384);              // 2048 B
    float* rootv  = (float*)(w + 16384 + 2048);
    float* c1root = (float*)(w + 16384 + 4096);
    float* s2v    = (float*)(w + 24576);                              // 2 MB
    float* hbuf   = (float*)(w + 24576 + 2097152);                    // 4 MB (2 branches)
    float* cbuf   = (float*)(w + 24576 + 2097152 + 4194304);          // 4 MB (2 branches)
    float* uebuf  = (float*)(w + 24576 + 2097152 + 4194304 + 4194304); // 12.29 MB (u then e)

    // WsWo/bias2 live in hbuf's space: consumed by k_oms before k_gemm1 writes hbuf
    float* WsWo  = hbuf;
    float* bias2 = hbuf + S2VD * W2V;

    hipMemsetAsync(d_ws, 0, 16384 + 2048, stream);

    // ---- independent prep ----
    k_deg<<<dim3((NEDGE + 255) / 256, 2), 256, 0, stream>>>(eiTD, eiBU, deg);
    k_wfold<<<75, 256, 0, stream>>>(s2v_w, out_proj_w, out_proj_b, s2v_b, WsWo, bias2);

    // ---- stage 1 ----
    k_qu <<<NPOSTS / 4, 320, 0, stream>>>(nodeText, embed_w, in_proj_w, in_proj_b, uebuf);
    k_att<<<NPOSTS / 2, 256, 0, stream>>>(nodeText, embed_w, uebuf);
    k_oms<<<NPOSTS / 4, 320, 0, stream>>>(uebuf, in_proj_w, in_proj_b, WsWo, bias2, s2v);

    // ---- stage 2 ----
    k_gemm1<<<dim3(NPOSTS / 16, 2), 256, 0, stream>>>(s2v, td_w1, bu_w1, td_b1, bu_b1, deg,
                                                      hbuf, cbuf);
    k_scat<<<dim3(NEDGE, 2), 256, 0, stream>>>(eiTD, eiBU, hbuf, deg, cbuf);

    k_root<<<dim3(1, 2), 256, 0, stream>>>(s2v, cbuf, td_w2, bu_w2, threadIdxP, rootv, c1root);

    k_gemm2<<<dim3(NPOSTS / 16, 2), 256, 0, stream>>>(cbuf, td_w2, bu_w2, td_b2, bu_b2, deg,
                                                      rootv, hbuf, cbuf);
    k_scat<<<dim3(NEDGE, 2), 256, 0, stream>>>(eiTD, eiBU, hbuf, deg, cbuf);

    k_reduce<<<dim3(NPOSTS / 32, 2), 256, 0, stream>>>(cbuf, msum);

    k_final<<<1, 256, 0, stream>>>(c1root, msum, fc_w, fc_b, outp);
}